// Round 6
// baseline (577.875 us; speedup 1.0000x reference)
//
#include <hip/hip_runtime.h>
#include <cfloat>
#include <climits>
#include <cstdint>

#define NPOINTS 32768
#define NBATCH  2
#define NLEV    4
#define NJOB    5          // 4 voxel levels + 1 point sort
#define PG      16         // point-sort grid
#define PCELLS  (PG*PG*PG)
#define NPB     128
#define NBLK    (NPOINTS / NPB)   // 256

struct BinJob {
  const float* coords;   // [B, N, 3]
  int* cnt; int* start; int* cur;
  float4* sorted;        // [B, N] {x,y,z,bitcast(idx)} in bin order
  int G, ncells, N;
  float invh;
};
struct BinParams { BinJob job[NJOB]; };

struct Level {
  const float4* sorted;  // [B, Nv] coords in bin order, .w = bit-cast original idx
  const int*    start;   // [B, ncells+1]
  int*          idxo;    // [B*Np*3], slot-indexed
  float*        wo;      // [B*Np*3], slot-indexed
  int G, ncells, Nv;
  float h, invh;
};
struct Params { Level lv[NLEV]; };

__device__ __forceinline__ int cell1d(float x, float invh, int G) {
  int c = (int)(x * invh);
  return min(max(c, 0), G - 1);
}

__global__ __launch_bounds__(256) void zero_kernel(int* __restrict__ p, int n)
{
  int i = blockIdx.x * 256 + threadIdx.x;
  if (i < n) p[i] = 0;
}

// ---------------- fused bin counts (all jobs) ----------------
__global__ __launch_bounds__(256) void count_kernel(BinParams prm)
{
  const BinJob J = prm.job[blockIdx.z];
  int v = blockIdx.x * 256 + threadIdx.x;
  int b = blockIdx.y;
  if (v >= J.N) return;
  const float* p = J.coords + ((size_t)b * J.N + v) * 3;
  int cx = cell1d(p[0], J.invh, J.G), cy = cell1d(p[1], J.invh, J.G), cz = cell1d(p[2], J.invh, J.G);
  atomicAdd(&J.cnt[b * J.ncells + (cz * J.G + cy) * J.G + cx], 1);
}

// ---------------- fused exclusive scan (one block per batch x job) ----------------
__global__ __launch_bounds__(1024) void scan_kernel(BinParams prm)
{
  const BinJob J = prm.job[blockIdx.y];
  const int b = blockIdx.x, t = threadIdx.x;
  const int ncells = J.ncells;
  const int* c  = J.cnt + (size_t)b * ncells;
  int* st = J.start + (size_t)b * (ncells + 1);
  int* cu = J.cur + (size_t)b * ncells;
  __shared__ int part[1024];
  const int chunk = (ncells + 1023) / 1024;
  const int lo = t * chunk, hi = min(lo + chunk, ncells);
  int s = 0;
  for (int i = lo; i < hi; ++i) s += c[i];
  part[t] = s;
  __syncthreads();
  for (int off = 1; off < 1024; off <<= 1) {
    int v = (t >= off) ? part[t - off] : 0;
    __syncthreads();
    part[t] += v;
    __syncthreads();
  }
  int base = (t > 0) ? part[t - 1] : 0;
  for (int i = lo; i < hi; ++i) { st[i] = base; cu[i] = base; base += c[i]; }
  if (t == 1023) st[ncells] = part[1023];
}

// ---------------- fused scatter: packed coords+idx into bin order ----------------
__global__ __launch_bounds__(256) void scatter_kernel(BinParams prm)
{
  const BinJob J = prm.job[blockIdx.z];
  int v = blockIdx.x * 256 + threadIdx.x;
  int b = blockIdx.y;
  if (v >= J.N) return;
  const float* p = J.coords + ((size_t)b * J.N + v) * 3;
  float x = p[0], y = p[1], z = p[2];
  int cx = cell1d(x, J.invh, J.G), cy = cell1d(y, J.invh, J.G), cz = cell1d(z, J.invh, J.G);
  int pos = atomicAdd(&J.cur[b * J.ncells + (cz * J.G + cy) * J.G + cx], 1);
  J.sorted[(size_t)b * J.N + pos] = make_float4(x, y, z, __int_as_float(v));
}

// ---------------- deterministic repair: sort points within each cell by idx ----------------
__global__ __launch_bounds__(256) void cellsort_kernel(
    float4* __restrict__ sorted, const int* __restrict__ start)
{
  int cid = blockIdx.x * 256 + threadIdx.x;
  if (cid >= NBATCH * PCELLS) return;
  int b = cid / PCELLS, cc = cid - b * PCELLS;
  const int* st = start + (size_t)b * (PCELLS + 1);
  float4* s = sorted + (size_t)b * NPOINTS;
  int ks = st[cc], ke = st[cc + 1];
  for (int i = ks + 1; i < ke; ++i) {        // insertion sort (cells are tiny)
    float4 v = s[i]; int key = __float_as_int(v.w);
    int j = i - 1;
    while (j >= ks && __float_as_int(s[j].w) > key) { s[j + 1] = s[j]; --j; }
    s[j + 1] = v;
  }
}

// ---------------- grid-pruned exact 3-NN query; 4 lanes/point, row-task parallel ----------------
__global__ __launch_bounds__(256) void query_kernel(
    const float4* __restrict__ psorted, Params prm)
{
  const int l = blockIdx.y, b = blockIdx.z;
  const Level L = prm.lv[l];
  const int tid = threadIdx.x;
  const int q = tid & 3;                        // quad lane
  const int sp = blockIdx.x * 64 + (tid >> 2);  // sorted point slot
  float4 pt = psorted[(size_t)b * NPOINTS + sp];
  const float px = pt.x, py = pt.y, pz = pt.z;
  const int G = L.G;
  const float h = L.h;

  const int cx = cell1d(px, L.invh, G);
  const int cy = cell1d(py, L.invh, G);
  const int cz = cell1d(pz, L.invh, G);
  const float fx = px - cx * h, fy = py - cy * h, fz = pz - cz * h;
  float m = fminf(fminf(fminf(fx, h - fx), fminf(fy, h - fy)), fminf(fz, h - fz));
  m = fmaxf(m, 0.f);

  const int* start     = L.start  + (size_t)b * (L.ncells + 1);
  const float4* sorted = L.sorted + (size_t)b * L.Nv;

  float b0 = FLT_MAX, b1 = FLT_MAX, b2 = FLT_MAX;
  int   i0 = INT_MAX, i1 = INT_MAX, i2 = INT_MAX;

  auto ins = [&](float d2, int vi) {
    if (d2 < b2 || (d2 == b2 && vi < i2)) {
      if (d2 < b1 || (d2 == b1 && vi < i1)) {
        b2 = b1; i2 = i1;
        if (d2 < b0 || (d2 == b0 && vi < i0)) { b1 = b0; i1 = i0; b0 = d2; i0 = vi; }
        else                                  { b1 = d2; i1 = vi; }
      } else { b2 = d2; i2 = vi; }
    }
  };
  auto scan_all = [&](int ks, int ke) {
    for (int k = ks; k < ke; ++k) {
      float4 vv = sorted[k];
      int vi = __float_as_int(vv.w);
      // exact reference arithmetic: individually-rounded squares, (x2+y2)+z2
      float dx = px - vv.x, dy = py - vv.y, dz = pz - vv.z;
      float d2 = __fadd_rn(__fadd_rn(__fmul_rn(dx, dx), __fmul_rn(dy, dy)),
                           __fmul_rn(dz, dz));
      ins(d2, vi);
    }
  };

  const int rmax = max(max(cx, G - 1 - cx), max(max(cy, G - 1 - cy), max(cz, G - 1 - cz)));
  int task = 0;   // uniform across the quad: round-robin whole x-range tasks to lanes
  for (int rho = 0; rho <= rmax; ++rho) {
    if (rho >= 1) {
      // quad-wide valid bound: union's true b2 <= min over lanes of local b2
      float bm = fminf(b2, __shfl_xor(b2, 1));
      bm = fminf(bm, __shfl_xor(bm, 2));
      float dmin = fmaxf((rho - 1) * h + m, 0.f);
      if (dmin * dmin * 0.99999f > bm) break;   // conservative exact-prune bound
    }
    const int z0 = max(cz - rho, 0), z1 = min(cz + rho, G - 1);
    const int y0 = max(cy - rho, 0), y1 = min(cy + rho, G - 1);
    for (int iz = z0; iz <= z1; ++iz) {
      const int adz = abs(iz - cz);
      for (int iy = y0; iy <= y1; ++iy) {
        const int ady = max(adz, abs(iy - cy));
        const int row = (iz * G + iy) * G;
        if (ady == rho) {
          const int x0 = max(cx - rho, 0), x1 = min(cx + rho, G - 1);
          if (((task++) & 3) == q) scan_all(start[row + x0], start[row + x1 + 1]);
        } else {
          const int xl = cx - rho, xr = cx + rho;
          if (xl >= 0)     { if (((task++) & 3) == q) scan_all(start[row + xl], start[row + xl + 1]); }
          if (xr <= G - 1) { if (((task++) & 3) == q) scan_all(start[row + xr], start[row + xr + 1]); }
        }
      }
    }
  }

  // merge the 4 lanes' sorted triples (deterministic, lex (d2, idx))
  #pragma unroll
  for (int mask = 1; mask <= 2; mask <<= 1) {
    float c0 = __shfl_xor(b0, mask), c1 = __shfl_xor(b1, mask), c2 = __shfl_xor(b2, mask);
    int   j0 = __shfl_xor(i0, mask), j1 = __shfl_xor(i1, mask), j2 = __shfl_xor(i2, mask);
    ins(c0, j0); ins(c1, j1); ins(c2, j2);
  }

  if (q == 0) {
    float w0 = 1.0f / (sqrtf(b0) + 1e-8f);
    float w1 = 1.0f / (sqrtf(b1) + 1e-8f);
    float w2 = 1.0f / (sqrtf(b2) + 1e-8f);
    float ws = (w0 + w1) + w2;
    size_t o = ((size_t)b * NPOINTS + sp) * 3;   // slot-indexed
    L.idxo[o] = i0; L.idxo[o + 1] = i1; L.idxo[o + 2] = i2;
    L.wo[o] = w0 / ws; L.wo[o + 1] = w1 / ws; L.wo[o + 2] = w2 / ws;
  }
}

// ---------------- Pass 1: gather-interp stats only (no out write), sorted-slot order ----------------
template <int C, int BDIM>
__global__ __launch_bounds__(BDIM) void interp_stats_kernel(
    const float* __restrict__ voxf, const int* __restrict__ idxo,
    const float* __restrict__ wo,
    float* __restrict__ psum, float* __restrict__ psq, int Nv)
{
  constexpr int C4 = C / 4;
  constexpr int R  = BDIM / C4;
  const int b = blockIdx.y, blk = blockIdx.x;
  const int tid = threadIdx.x;
  const int r = tid / C4, c4 = tid - r * C4;
  const float4* fb = (const float4*)(voxf + (size_t)b * Nv * C);
  const int p0 = blk * NPB;

  float4 s = make_float4(0, 0, 0, 0), q = make_float4(0, 0, 0, 0);
  for (int sp = p0 + r; sp < p0 + NPB; sp += R) {
    size_t pg = ((size_t)b * NPOINTS + sp) * 3;
    int   ia = idxo[pg], ib = idxo[pg + 1], ic = idxo[pg + 2];
    float wa = wo[pg],   wb = wo[pg + 1],   wc = wo[pg + 2];
    float4 fa = fb[(size_t)ia * C4 + c4];
    float4 f2 = fb[(size_t)ib * C4 + c4];
    float4 fc = fb[(size_t)ic * C4 + c4];
    float4 o;
    o.x = wa * fa.x + wb * f2.x + wc * fc.x;
    o.y = wa * fa.y + wb * f2.y + wc * fc.y;
    o.z = wa * fa.z + wb * f2.z + wc * fc.z;
    o.w = wa * fa.w + wb * f2.w + wc * fc.w;
    s.x += o.x; s.y += o.y; s.z += o.z; s.w += o.w;
    q.x += o.x * o.x; q.y += o.y * o.y; q.z += o.z * o.z; q.w += o.w * o.w;
  }

  __shared__ float4 ls[BDIM];
  ls[tid] = s;
  __syncthreads();
  if (r == 0) {
    float4 tot = s;
    #pragma unroll
    for (int rr = 1; rr < R; ++rr) {
      float4 v = ls[c4 + rr * C4];
      tot.x += v.x; tot.y += v.y; tot.z += v.z; tot.w += v.w;
    }
    ((float4*)psum)[((size_t)b * NBLK + blk) * C4 + c4] = tot;
  }
  __syncthreads();
  ls[tid] = q;
  __syncthreads();
  if (r == 0) {
    float4 tot = q;
    #pragma unroll
    for (int rr = 1; rr < R; ++rr) {
      float4 v = ls[c4 + rr * C4];
      tot.x += v.x; tot.y += v.y; tot.z += v.z; tot.w += v.w;
    }
    ((float4*)psq)[((size_t)b * NBLK + blk) * C4 + c4] = tot;
  }
}

// ---------------- BN stats (parallel reduce over NBLK partials) ----------------
__global__ __launch_bounds__(256) void bn_stats_kernel(
    const float* __restrict__ psum, const float* __restrict__ psq,
    const float* __restrict__ gamma, const float* __restrict__ beta,
    float* __restrict__ scale, float* __restrict__ shift, int C, float invN)
{
  const int c = blockIdx.x, b = blockIdx.y, t = threadIdx.x;
  float s = 0.f, q = 0.f;
  for (int k = t; k < NBLK; k += 256) {
    s += psum[((size_t)b * NBLK + k) * C + c];
    q += psq[((size_t)b * NBLK + k) * C + c];
  }
  __shared__ float ss[256], qs[256];
  ss[t] = s; qs[t] = q;
  __syncthreads();
  for (int o = 128; o > 0; o >>= 1) {
    if (t < o) { ss[t] += ss[t + o]; qs[t] += qs[t + o]; }
    __syncthreads();
  }
  if (t == 0) {
    float mu  = ss[0] * invN;
    float var = fmaxf(qs[0] * invN - mu * mu, 0.f);
    float sc  = gamma[c] * rsqrtf(var + 1e-5f);
    scale[b * C + c] = sc;
    shift[b * C + c] = beta[c] - mu * sc;
  }
}

// ---------------- Pass 2: re-gather, normalize, scatter-write to original ids ----------------
template <int C, int BDIM>
__global__ __launch_bounds__(BDIM) void interp_apply_kernel(
    const float* __restrict__ voxf, const int* __restrict__ idxo,
    const float* __restrict__ wo, const float4* __restrict__ psorted,
    const float* __restrict__ scale, const float* __restrict__ shift,
    float* __restrict__ out, int Nv)
{
  constexpr int C4 = C / 4;
  constexpr int R  = BDIM / C4;
  const int b = blockIdx.y, blk = blockIdx.x;
  const int tid = threadIdx.x;
  const int r = tid / C4, c4 = tid - r * C4;
  const float4* fb = (const float4*)(voxf + (size_t)b * Nv * C);
  float4* ob = (float4*)(out + (size_t)b * NPOINTS * C);
  const float4 sc = ((const float4*)scale)[b * C4 + c4];
  const float4 sh = ((const float4*)shift)[b * C4 + c4];
  const int p0 = blk * NPB;

  for (int sp = p0 + r; sp < p0 + NPB; sp += R) {
    int p = __float_as_int(psorted[(size_t)b * NPOINTS + sp].w);  // original id
    size_t pg = ((size_t)b * NPOINTS + sp) * 3;
    int   ia = idxo[pg], ib = idxo[pg + 1], ic = idxo[pg + 2];
    float wa = wo[pg],   wb = wo[pg + 1],   wc = wo[pg + 2];
    float4 fa = fb[(size_t)ia * C4 + c4];
    float4 f2 = fb[(size_t)ib * C4 + c4];
    float4 fc = fb[(size_t)ic * C4 + c4];
    float4 o;
    o.x = fmaf(wa * fa.x + wb * f2.x + wc * fc.x, sc.x, sh.x);
    o.y = fmaf(wa * fa.y + wb * f2.y + wc * fc.y, sc.y, sh.y);
    o.z = fmaf(wa * fa.z + wb * f2.z + wc * fc.z, sc.z, sh.z);
    o.w = fmaf(wa * fa.w + wb * f2.w + wc * fc.w, sc.w, sh.w);
    ob[(size_t)p * C4 + c4] = o;
  }
}

// ---------------- Host launch ----------------
extern "C" void kernel_launch(void* const* d_in, const int* in_sizes, int n_in,
                              void* d_out, int out_size, void* d_ws, size_t ws_size,
                              hipStream_t stream)
{
  const float* ptc = (const float*)d_in[0];
  static const int    Cs[4]     = {256, 128, 96, 96};
  static const int    Nvs[4]    = {2048, 6144, 16384, 32768};
  static const int    Gs[4]     = {13, 18, 25, 32};   // ~1 voxel/cell
  static const size_t outOff[4] = {0, 16777216, 25165824, 31457280};

  // ---- workspace carve ----
  size_t off = 0;
  auto carve = [&](size_t bytes) {
    off = (off + 255) & ~(size_t)255;
    size_t o = off; off += bytes; return o;
  };
  char* w = (char*)d_ws;

  int nc[NJOB];
  for (int l = 0; l < 4; ++l) nc[l] = Gs[l] * Gs[l] * Gs[l];
  nc[4] = PCELLS;
  int Ns[NJOB] = {Nvs[0], Nvs[1], Nvs[2], Nvs[3], NPOINTS};
  int Gj[NJOB] = {Gs[0], Gs[1], Gs[2], Gs[3], PG};

  // contiguous counter block (zeroed with one launch)
  int totcnt = 0;
  for (int j = 0; j < NJOB; ++j) totcnt += nc[j];
  int* cntbase = (int*)(w + carve((size_t)NBATCH * totcnt * 4));

  float4* sortedj[NJOB]; int* cntj[NJOB]; int* sttj[NJOB]; int* curj[NJOB];
  {
    int acc = 0;
    for (int j = 0; j < NJOB; ++j) {
      cntj[j] = cntbase + (size_t)NBATCH * acc;
      acc += nc[j];
    }
  }
  for (int j = 0; j < NJOB; ++j) {
    sortedj[j] = (float4*)(w + carve((size_t)NBATCH * Ns[j] * 16));
    sttj[j]    = (int*)   (w + carve((size_t)NBATCH * (nc[j] + 1) * 4));
    curj[j]    = (int*)   (w + carve((size_t)NBATCH * nc[j] * 4));
  }
  int*   idxo  = (int*)  (w + carve((size_t)NLEV * NBATCH * NPOINTS * 3 * 4));
  float* wo    = (float*)(w + carve((size_t)NLEV * NBATCH * NPOINTS * 3 * 4));
  float* psum  = (float*)(w + carve((size_t)NBATCH * NBLK * 256 * 4));
  float* psq   = (float*)(w + carve((size_t)NBATCH * NBLK * 256 * 4));
  float* scale = (float*)(w + carve((size_t)NBATCH * 256 * 4));
  float* shift = (float*)(w + carve((size_t)NBATCH * 256 * 4));

  BinParams bp;
  for (int j = 0; j < NJOB; ++j) {
    BinJob& J = bp.job[j];
    J.coords = (j < 4) ? (const float*)d_in[1 + 4 * j] : ptc;
    J.cnt = cntj[j]; J.start = sttj[j]; J.cur = curj[j]; J.sorted = sortedj[j];
    J.G = Gj[j]; J.ncells = nc[j]; J.N = Ns[j];
    J.invh = Gj[j] / 50.0f;
  }

  Params prm;
  for (int l = 0; l < 4; ++l) {
    Level& L = prm.lv[l];
    L.sorted = sortedj[l]; L.start = sttj[l];
    L.idxo = idxo + (size_t)l * NBATCH * NPOINTS * 3;
    L.wo   = wo   + (size_t)l * NBATCH * NPOINTS * 3;
    L.G = Gs[l]; L.ncells = nc[l]; L.Nv = Nvs[l];
    L.h = 50.0f / Gs[l]; L.invh = Gs[l] / 50.0f;
  }

  // ---- fused binning: zero, count, scan, scatter (all 5 jobs) + point-cell sort repair ----
  const int zn = NBATCH * totcnt;
  zero_kernel<<<(zn + 255) / 256, 256, 0, stream>>>(cntbase, zn);
  count_kernel<<<dim3((NPOINTS + 255) / 256, NBATCH, NJOB), 256, 0, stream>>>(bp);
  scan_kernel<<<dim3(NBATCH, NJOB), 1024, 0, stream>>>(bp);
  scatter_kernel<<<dim3((NPOINTS + 255) / 256, NBATCH, NJOB), 256, 0, stream>>>(bp);
  cellsort_kernel<<<(NBATCH * PCELLS + 255) / 256, 256, 0, stream>>>(sortedj[4], sttj[4]);

  // ---- fused exact 3-NN query over all levels (4 lanes/point, row-task parallel) ----
  query_kernel<<<dim3(NPOINTS / 64, NLEV, NBATCH), 256, 0, stream>>>(sortedj[4], prm);

  // ---- per-level: stats pass -> BN stats -> fused apply pass ----
  for (int l = 0; l < 4; ++l) {
    const float* voxf  = (const float*)d_in[2 + 4 * l];
    const float* gamma = (const float*)d_in[3 + 4 * l];
    const float* beta  = (const float*)d_in[4 + 4 * l];
    const int C = Cs[l], Nv = Nvs[l];
    float* outl = (float*)d_out + outOff[l];
    const int* idl = idxo + (size_t)l * NBATCH * NPOINTS * 3;
    const float* wl = wo  + (size_t)l * NBATCH * NPOINTS * 3;

    if (C == 256)
      interp_stats_kernel<256, 256><<<dim3(NBLK, NBATCH), 256, 0, stream>>>(
          voxf, idl, wl, psum, psq, Nv);
    else if (C == 128)
      interp_stats_kernel<128, 256><<<dim3(NBLK, NBATCH), 256, 0, stream>>>(
          voxf, idl, wl, psum, psq, Nv);
    else
      interp_stats_kernel<96, 240><<<dim3(NBLK, NBATCH), 240, 0, stream>>>(
          voxf, idl, wl, psum, psq, Nv);

    bn_stats_kernel<<<dim3(C, NBATCH), 256, 0, stream>>>(
        psum, psq, gamma, beta, scale, shift, C, 1.0f / NPOINTS);

    if (C == 256)
      interp_apply_kernel<256, 256><<<dim3(NBLK, NBATCH), 256, 0, stream>>>(
          voxf, idl, wl, sortedj[4], scale, shift, outl, Nv);
    else if (C == 128)
      interp_apply_kernel<128, 256><<<dim3(NBLK, NBATCH), 256, 0, stream>>>(
          voxf, idl, wl, sortedj[4], scale, shift, outl, Nv);
    else
      interp_apply_kernel<96, 240><<<dim3(NBLK, NBATCH), 240, 0, stream>>>(
          voxf, idl, wl, sortedj[4], scale, shift, outl, Nv);
  }
}

// Round 7
// 375.304 us; speedup vs baseline: 1.5398x; 1.5398x over previous
//
#include <hip/hip_runtime.h>
#include <cfloat>
#include <climits>
#include <cstdint>

#define NPOINTS 32768
#define NBATCH  2
#define NLEV    4
#define NJOB    5          // 4 voxel levels + 1 point sort
#define PG      16         // point-sort grid
#define PCELLS  (PG*PG*PG)
#define NPB     128
#define NBLK    (NPOINTS / NPB)   // 256

struct BinJob {
  const float* coords;   // [B, N, 3]
  int* cnt; int* start; int* cur;
  float4* sorted;        // [B, N] {x,y,z,bitcast(idx)} in bin order
  int G, ncells, N;
  float invh;
};
struct BinParams { BinJob job[NJOB]; };

struct Level {
  const float4* sorted;  // [B, Nv] coords in bin order, .w = bit-cast original idx
  const int*    start;   // [B, ncells+1]
  int*          idxo;    // [B*Np*3], slot-indexed
  float*        wo;      // [B*Np*3], slot-indexed
  int G, ncells, Nv;
  float h, invh;
};
struct Params { Level lv[NLEV]; };

__device__ __forceinline__ int cell1d(float x, float invh, int G) {
  int c = (int)(x * invh);
  return min(max(c, 0), G - 1);
}

__global__ __launch_bounds__(256) void zero_kernel(int* __restrict__ p, int n)
{
  int i = blockIdx.x * 256 + threadIdx.x;
  if (i < n) p[i] = 0;
}

// ---------------- fused bin counts (all jobs) ----------------
__global__ __launch_bounds__(256) void count_kernel(BinParams prm)
{
  const BinJob J = prm.job[blockIdx.z];
  int v = blockIdx.x * 256 + threadIdx.x;
  int b = blockIdx.y;
  if (v >= J.N) return;
  const float* p = J.coords + ((size_t)b * J.N + v) * 3;
  int cx = cell1d(p[0], J.invh, J.G), cy = cell1d(p[1], J.invh, J.G), cz = cell1d(p[2], J.invh, J.G);
  atomicAdd(&J.cnt[b * J.ncells + (cz * J.G + cy) * J.G + cx], 1);
}

// ---------------- fused exclusive scan (one block per batch x job) ----------------
__global__ __launch_bounds__(1024) void scan_kernel(BinParams prm)
{
  const BinJob J = prm.job[blockIdx.y];
  const int b = blockIdx.x, t = threadIdx.x;
  const int ncells = J.ncells;
  const int* c  = J.cnt + (size_t)b * ncells;
  int* st = J.start + (size_t)b * (ncells + 1);
  int* cu = J.cur + (size_t)b * ncells;
  __shared__ int part[1024];
  const int chunk = (ncells + 1023) / 1024;
  const int lo = t * chunk, hi = min(lo + chunk, ncells);
  int s = 0;
  for (int i = lo; i < hi; ++i) s += c[i];
  part[t] = s;
  __syncthreads();
  for (int off = 1; off < 1024; off <<= 1) {
    int v = (t >= off) ? part[t - off] : 0;
    __syncthreads();
    part[t] += v;
    __syncthreads();
  }
  int base = (t > 0) ? part[t - 1] : 0;
  for (int i = lo; i < hi; ++i) { st[i] = base; cu[i] = base; base += c[i]; }
  if (t == 1023) st[ncells] = part[1023];
}

// ---------------- fused scatter: packed coords+idx into bin order ----------------
__global__ __launch_bounds__(256) void scatter_kernel(BinParams prm)
{
  const BinJob J = prm.job[blockIdx.z];
  int v = blockIdx.x * 256 + threadIdx.x;
  int b = blockIdx.y;
  if (v >= J.N) return;
  const float* p = J.coords + ((size_t)b * J.N + v) * 3;
  float x = p[0], y = p[1], z = p[2];
  int cx = cell1d(x, J.invh, J.G), cy = cell1d(y, J.invh, J.G), cz = cell1d(z, J.invh, J.G);
  int pos = atomicAdd(&J.cur[b * J.ncells + (cz * J.G + cy) * J.G + cx], 1);
  J.sorted[(size_t)b * J.N + pos] = make_float4(x, y, z, __int_as_float(v));
}

// ---------------- deterministic repair: sort points within each cell by idx ----------------
__global__ __launch_bounds__(256) void cellsort_kernel(
    float4* __restrict__ sorted, const int* __restrict__ start)
{
  int cid = blockIdx.x * 256 + threadIdx.x;
  if (cid >= NBATCH * PCELLS) return;
  int b = cid / PCELLS, cc = cid - b * PCELLS;
  const int* st = start + (size_t)b * (PCELLS + 1);
  float4* s = sorted + (size_t)b * NPOINTS;
  int ks = st[cc], ke = st[cc + 1];
  for (int i = ks + 1; i < ke; ++i) {        // insertion sort (cells are tiny)
    float4 v = s[i]; int key = __float_as_int(v.w);
    int j = i - 1;
    while (j >= ks && __float_as_int(s[j].w) > key) { s[j + 1] = s[j]; --j; }
    s[j + 1] = v;
  }
}

// ---- grid-pruned exact 3-NN query; hoisted 27-cell block + rare ring tail ----
__global__ __launch_bounds__(256) void query_kernel(
    const float4* __restrict__ psorted, Params prm)
{
  const int l = blockIdx.y, b = blockIdx.z;
  const Level L = prm.lv[l];
  const int tid = threadIdx.x;
  const int q = tid & 3;                        // quad lane
  const int sp = blockIdx.x * 64 + (tid >> 2);  // sorted point slot
  float4 pt = psorted[(size_t)b * NPOINTS + sp];
  const float px = pt.x, py = pt.y, pz = pt.z;
  const int G = L.G;
  const float h = L.h;

  const int cx = cell1d(px, L.invh, G);
  const int cy = cell1d(py, L.invh, G);
  const int cz = cell1d(pz, L.invh, G);
  const float fx = px - cx * h, fy = py - cy * h, fz = pz - cz * h;
  float m = fminf(fminf(fminf(fx, h - fx), fminf(fy, h - fy)), fminf(fz, h - fz));
  m = fmaxf(m, 0.f);

  const int* start     = L.start  + (size_t)b * (L.ncells + 1);
  const float4* sorted = L.sorted + (size_t)b * L.Nv;

  float b0 = FLT_MAX, b1 = FLT_MAX, b2 = FLT_MAX;
  int   i0 = INT_MAX, i1 = INT_MAX, i2 = INT_MAX;

  auto ins = [&](float d2, int vi) {
    if (d2 < b2 || (d2 == b2 && vi < i2)) {
      if (d2 < b1 || (d2 == b1 && vi < i1)) {
        b2 = b1; i2 = i1;
        if (d2 < b0 || (d2 == b0 && vi < i0)) { b1 = b0; i1 = i0; b0 = d2; i0 = vi; }
        else                                  { b1 = d2; i1 = vi; }
      } else { b2 = d2; i2 = vi; }
    }
  };
  auto cand = [&](int k) {
    float4 vv = sorted[k];
    int vi = __float_as_int(vv.w);
    // exact reference arithmetic: individually-rounded squares, (x2+y2)+z2
    float dx = px - vv.x, dy = py - vv.y, dz = pz - vv.z;
    float d2 = __fadd_rn(__fadd_rn(__fmul_rn(dx, dx), __fmul_rn(dy, dy)),
                         __fmul_rn(dz, dz));
    ins(d2, vi);
  };
  auto scan_range = [&](int ks, int ke) {
    for (int k = ks + q; k < ke; k += 4) cand(k);
  };

  // ---- Phase 1: hoisted 3x3x3 block (rho<=1), all bound loads issued up front ----
  {
    const int x0 = max(cx - 1, 0), x1 = min(cx + 1, G - 1);
    int ks9[9], ke9[9];
    #pragma unroll
    for (int i = 0; i < 9; ++i) {
      const int dz = i / 3 - 1, dy = i % 3 - 1;
      const int iz = cz + dz, iy = cy + dy;
      const bool ok = (iz >= 0) && (iz < G) && (iy >= 0) && (iy < G);
      const int row = (iz * G + iy) * G;
      const int sa = ok ? (row + x0) : 0;
      const int sb = ok ? (row + x1 + 1) : 0;
      int a = start[sa], e = start[sb];     // 18 independent loads, pipelined
      if (!ok) { a = 0; e = 0; }
      ks9[i] = a; ke9[i] = e;
    }
    #pragma unroll
    for (int i = 0; i < 9; ++i) scan_range(ks9[i], ke9[i]);
  }

  // ---- Phase 2: rare ring tail from rho=2 ----
  {
    float bm = fminf(b2, __shfl_xor(b2, 1));
    bm = fminf(bm, __shfl_xor(bm, 2));
    float dmin = h + m;                     // lower bound for rho=2
    if (dmin * dmin * 0.99999f <= bm) {
      const int rmax = max(max(cx, G - 1 - cx), max(max(cy, G - 1 - cy), max(cz, G - 1 - cz)));
      for (int rho = 2; rho <= rmax; ++rho) {
        float bmm = fminf(b2, __shfl_xor(b2, 1));
        bmm = fminf(bmm, __shfl_xor(bmm, 2));
        float dmn = fmaxf((rho - 1) * h + m, 0.f);
        if (dmn * dmn * 0.99999f > bmm) break;   // conservative exact-prune bound
        const int z0 = max(cz - rho, 0), z1 = min(cz + rho, G - 1);
        const int y0 = max(cy - rho, 0), y1 = min(cy + rho, G - 1);
        for (int iz = z0; iz <= z1; ++iz) {
          const int adz = abs(iz - cz);
          for (int iy = y0; iy <= y1; ++iy) {
            const int ady = max(adz, abs(iy - cy));
            const int row = (iz * G + iy) * G;
            if (ady == rho) {
              const int x0 = max(cx - rho, 0), x1 = min(cx + rho, G - 1);
              scan_range(start[row + x0], start[row + x1 + 1]);
            } else {
              const int xl = cx - rho, xr = cx + rho;
              if (xl >= 0)     scan_range(start[row + xl], start[row + xl + 1]);
              if (xr <= G - 1) scan_range(start[row + xr], start[row + xr + 1]);
            }
          }
        }
      }
    }
  }

  // merge the 4 lanes' sorted triples (deterministic, lex (d2, idx))
  #pragma unroll
  for (int mask = 1; mask <= 2; mask <<= 1) {
    float c0 = __shfl_xor(b0, mask), c1 = __shfl_xor(b1, mask), c2 = __shfl_xor(b2, mask);
    int   j0 = __shfl_xor(i0, mask), j1 = __shfl_xor(i1, mask), j2 = __shfl_xor(i2, mask);
    ins(c0, j0); ins(c1, j1); ins(c2, j2);
  }

  if (q == 0) {
    float w0 = 1.0f / (sqrtf(b0) + 1e-8f);
    float w1 = 1.0f / (sqrtf(b1) + 1e-8f);
    float w2 = 1.0f / (sqrtf(b2) + 1e-8f);
    float ws = (w0 + w1) + w2;
    size_t o = ((size_t)b * NPOINTS + sp) * 3;   // slot-indexed
    L.idxo[o] = i0; L.idxo[o + 1] = i1; L.idxo[o + 2] = i2;
    L.wo[o] = w0 / ws; L.wo[o + 1] = w1 / ws; L.wo[o + 2] = w2 / ws;
  }
}

// ---- Gather-interp in sorted-slot order; write rows at original ids; block stats ----
template <int C, int BDIM>
__global__ __launch_bounds__(BDIM) void interp_kernel(
    const float* __restrict__ voxf, const int* __restrict__ idxo,
    const float* __restrict__ wo, const float4* __restrict__ psorted,
    float* __restrict__ out, float* __restrict__ psum, float* __restrict__ psq,
    int Nv)
{
  constexpr int C4 = C / 4;
  constexpr int R  = BDIM / C4;
  const int b = blockIdx.y, blk = blockIdx.x;
  const int tid = threadIdx.x;
  const int r = tid / C4, c4 = tid - r * C4;
  const float4* fb = (const float4*)(voxf + (size_t)b * Nv * C);
  float4* ob = (float4*)(out + (size_t)b * NPOINTS * C);
  const int p0 = blk * NPB;

  float4 s = make_float4(0, 0, 0, 0), q = make_float4(0, 0, 0, 0);
  for (int sp = p0 + r; sp < p0 + NPB; sp += R) {
    int p = __float_as_int(psorted[(size_t)b * NPOINTS + sp].w);  // original id
    size_t pg = ((size_t)b * NPOINTS + sp) * 3;
    int   ia = idxo[pg], ib = idxo[pg + 1], ic = idxo[pg + 2];
    float wa = wo[pg],   wb = wo[pg + 1],   wc = wo[pg + 2];
    float4 fa = fb[(size_t)ia * C4 + c4];
    float4 f2 = fb[(size_t)ib * C4 + c4];
    float4 fc = fb[(size_t)ic * C4 + c4];
    float4 o;
    o.x = wa * fa.x + wb * f2.x + wc * fc.x;
    o.y = wa * fa.y + wb * f2.y + wc * fc.y;
    o.z = wa * fa.z + wb * f2.z + wc * fc.z;
    o.w = wa * fa.w + wb * f2.w + wc * fc.w;
    ob[(size_t)p * C4 + c4] = o;
    s.x += o.x; s.y += o.y; s.z += o.z; s.w += o.w;
    q.x += o.x * o.x; q.y += o.y * o.y; q.z += o.z * o.z; q.w += o.w * o.w;
  }

  __shared__ float4 ls[BDIM];
  ls[tid] = s;
  __syncthreads();
  if (r == 0) {
    float4 tot = s;
    #pragma unroll
    for (int rr = 1; rr < R; ++rr) {
      float4 v = ls[c4 + rr * C4];
      tot.x += v.x; tot.y += v.y; tot.z += v.z; tot.w += v.w;
    }
    ((float4*)psum)[((size_t)b * NBLK + blk) * C4 + c4] = tot;
  }
  __syncthreads();
  ls[tid] = q;
  __syncthreads();
  if (r == 0) {
    float4 tot = q;
    #pragma unroll
    for (int rr = 1; rr < R; ++rr) {
      float4 v = ls[c4 + rr * C4];
      tot.x += v.x; tot.y += v.y; tot.z += v.z; tot.w += v.w;
    }
    ((float4*)psq)[((size_t)b * NBLK + blk) * C4 + c4] = tot;
  }
}

// ---------------- BN stats (parallel reduce over NBLK partials) ----------------
__global__ __launch_bounds__(256) void bn_stats_kernel(
    const float* __restrict__ psum, const float* __restrict__ psq,
    const float* __restrict__ gamma, const float* __restrict__ beta,
    float* __restrict__ scale, float* __restrict__ shift, int C, float invN)
{
  const int c = blockIdx.x, b = blockIdx.y, t = threadIdx.x;
  float s = 0.f, q = 0.f;
  for (int k = t; k < NBLK; k += 256) {
    s += psum[((size_t)b * NBLK + k) * C + c];
    q += psq[((size_t)b * NBLK + k) * C + c];
  }
  __shared__ float ss[256], qs[256];
  ss[t] = s; qs[t] = q;
  __syncthreads();
  for (int o = 128; o > 0; o >>= 1) {
    if (t < o) { ss[t] += ss[t + o]; qs[t] += qs[t + o]; }
    __syncthreads();
  }
  if (t == 0) {
    float mu  = ss[0] * invN;
    float var = fmaxf(qs[0] * invN - mu * mu, 0.f);
    float sc  = gamma[c] * rsqrtf(var + 1e-5f);
    scale[b * C + c] = sc;
    shift[b * C + c] = beta[c] - mu * sc;
  }
}

// ---------------- In-place normalize (float4) ----------------
__global__ __launch_bounds__(256) void bn_apply_kernel(
    float* __restrict__ out, const float* __restrict__ scale,
    const float* __restrict__ shift, int C, int NpC)
{
  const int e = blockIdx.x * 256 + threadIdx.x;
  const int npc4 = NpC >> 2, c4n = C >> 2;
  const int b = e / npc4;
  const int rem = e - b * npc4;
  const int c4 = rem % c4n;
  float4 v  = ((float4*)out)[e];
  float4 sc = ((const float4*)scale)[b * c4n + c4];
  float4 sh = ((const float4*)shift)[b * c4n + c4];
  v.x = fmaf(v.x, sc.x, sh.x);
  v.y = fmaf(v.y, sc.y, sh.y);
  v.z = fmaf(v.z, sc.z, sh.z);
  v.w = fmaf(v.w, sc.w, sh.w);
  ((float4*)out)[e] = v;
}

// ---------------- Host launch ----------------
extern "C" void kernel_launch(void* const* d_in, const int* in_sizes, int n_in,
                              void* d_out, int out_size, void* d_ws, size_t ws_size,
                              hipStream_t stream)
{
  const float* ptc = (const float*)d_in[0];
  static const int    Cs[4]     = {256, 128, 96, 96};
  static const int    Nvs[4]    = {2048, 6144, 16384, 32768};
  static const int    Gs[4]     = {10, 14, 18, 22};   // ~2-3 voxels/cell (R5-proven)
  static const size_t outOff[4] = {0, 16777216, 25165824, 31457280};

  // ---- workspace carve ----
  size_t off = 0;
  auto carve = [&](size_t bytes) {
    off = (off + 255) & ~(size_t)255;
    size_t o = off; off += bytes; return o;
  };
  char* w = (char*)d_ws;

  int nc[NJOB];
  for (int l = 0; l < 4; ++l) nc[l] = Gs[l] * Gs[l] * Gs[l];
  nc[4] = PCELLS;
  int Ns[NJOB] = {Nvs[0], Nvs[1], Nvs[2], Nvs[3], NPOINTS};
  int Gj[NJOB] = {Gs[0], Gs[1], Gs[2], Gs[3], PG};

  // contiguous counter block (zeroed with one launch)
  int totcnt = 0;
  for (int j = 0; j < NJOB; ++j) totcnt += nc[j];
  int* cntbase = (int*)(w + carve((size_t)NBATCH * totcnt * 4));

  float4* sortedj[NJOB]; int* cntj[NJOB]; int* sttj[NJOB]; int* curj[NJOB];
  {
    int acc = 0;
    for (int j = 0; j < NJOB; ++j) {
      cntj[j] = cntbase + (size_t)NBATCH * acc;
      acc += nc[j];
    }
  }
  for (int j = 0; j < NJOB; ++j) {
    sortedj[j] = (float4*)(w + carve((size_t)NBATCH * Ns[j] * 16));
    sttj[j]    = (int*)   (w + carve((size_t)NBATCH * (nc[j] + 1) * 4));
    curj[j]    = (int*)   (w + carve((size_t)NBATCH * nc[j] * 4));
  }
  int*   idxo  = (int*)  (w + carve((size_t)NLEV * NBATCH * NPOINTS * 3 * 4));
  float* wo    = (float*)(w + carve((size_t)NLEV * NBATCH * NPOINTS * 3 * 4));
  float* psum  = (float*)(w + carve((size_t)NBATCH * NBLK * 256 * 4));
  float* psq   = (float*)(w + carve((size_t)NBATCH * NBLK * 256 * 4));
  float* scale = (float*)(w + carve((size_t)NBATCH * 256 * 4));
  float* shift = (float*)(w + carve((size_t)NBATCH * 256 * 4));

  BinParams bp;
  for (int j = 0; j < NJOB; ++j) {
    BinJob& J = bp.job[j];
    J.coords = (j < 4) ? (const float*)d_in[1 + 4 * j] : ptc;
    J.cnt = cntj[j]; J.start = sttj[j]; J.cur = curj[j]; J.sorted = sortedj[j];
    J.G = Gj[j]; J.ncells = nc[j]; J.N = Ns[j];
    J.invh = Gj[j] / 50.0f;
  }

  Params prm;
  for (int l = 0; l < 4; ++l) {
    Level& L = prm.lv[l];
    L.sorted = sortedj[l]; L.start = sttj[l];
    L.idxo = idxo + (size_t)l * NBATCH * NPOINTS * 3;
    L.wo   = wo   + (size_t)l * NBATCH * NPOINTS * 3;
    L.G = Gs[l]; L.ncells = nc[l]; L.Nv = Nvs[l];
    L.h = 50.0f / Gs[l]; L.invh = Gs[l] / 50.0f;
  }

  // ---- fused binning + point-cell sort repair ----
  const int zn = NBATCH * totcnt;
  zero_kernel<<<(zn + 255) / 256, 256, 0, stream>>>(cntbase, zn);
  count_kernel<<<dim3((NPOINTS + 255) / 256, NBATCH, NJOB), 256, 0, stream>>>(bp);
  scan_kernel<<<dim3(NBATCH, NJOB), 1024, 0, stream>>>(bp);
  scatter_kernel<<<dim3((NPOINTS + 255) / 256, NBATCH, NJOB), 256, 0, stream>>>(bp);
  cellsort_kernel<<<(NBATCH * PCELLS + 255) / 256, 256, 0, stream>>>(sortedj[4], sttj[4]);

  // ---- fused exact 3-NN query (hoisted 27-cell block, 4 lanes/point) ----
  query_kernel<<<dim3(NPOINTS / 64, NLEV, NBATCH), 256, 0, stream>>>(sortedj[4], prm);

  // ---- per-level: interp(+stats) -> BN stats -> in-place apply ----
  for (int l = 0; l < 4; ++l) {
    const float* voxf  = (const float*)d_in[2 + 4 * l];
    const float* gamma = (const float*)d_in[3 + 4 * l];
    const float* beta  = (const float*)d_in[4 + 4 * l];
    const int C = Cs[l], Nv = Nvs[l];
    float* outl = (float*)d_out + outOff[l];
    const int* idl = idxo + (size_t)l * NBATCH * NPOINTS * 3;
    const float* wl = wo  + (size_t)l * NBATCH * NPOINTS * 3;

    if (C == 256)
      interp_kernel<256, 256><<<dim3(NBLK, NBATCH), 256, 0, stream>>>(
          voxf, idl, wl, sortedj[4], outl, psum, psq, Nv);
    else if (C == 128)
      interp_kernel<128, 256><<<dim3(NBLK, NBATCH), 256, 0, stream>>>(
          voxf, idl, wl, sortedj[4], outl, psum, psq, Nv);
    else
      interp_kernel<96, 240><<<dim3(NBLK, NBATCH), 240, 0, stream>>>(
          voxf, idl, wl, sortedj[4], outl, psum, psq, Nv);

    bn_stats_kernel<<<dim3(C, NBATCH), 256, 0, stream>>>(
        psum, psq, gamma, beta, scale, shift, C, 1.0f / NPOINTS);

    const int n4 = NBATCH * NPOINTS * C / 4;
    bn_apply_kernel<<<n4 / 256, 256, 0, stream>>>(
        (float*)outl, scale, shift, C, NPOINTS * C);
  }
}